// Round 5
// baseline (161.371 us; speedup 1.0000x reference)
//
#include <hip/hip_runtime.h>
#include <hip/hip_bf16.h>

typedef float f4v __attribute__((ext_vector_type(4)));
typedef float f32x4 __attribute__((ext_vector_type(4)));
typedef __bf16 bf16x8 __attribute__((ext_vector_type(8)));

#define GLDS16(gsrc, ldst)                                                  \
  __builtin_amdgcn_global_load_lds(                                         \
      (const __attribute__((address_space(1))) unsigned int*)(gsrc),        \
      (__attribute__((address_space(3))) unsigned int*)(ldst), 16, 0, 0)

__device__ __forceinline__ unsigned pack2bf(float lo, float hi) {
  unsigned short ua = __builtin_bit_cast(unsigned short, (__bf16)lo);
  unsigned short ub = __builtin_bit_cast(unsigned short, (__bf16)hi);
  return (unsigned)ua | ((unsigned)ub << 16);
}

// ---------------- kernel 1: modulation MLP -> s [16][512] (f32, ws) -------
__global__ __launch_bounds__(256) void mlp_kernel(
    const float* __restrict__ t,
    const float* __restrict__ W1, const float* __restrict__ b1,
    const float* __restrict__ W2, const float* __restrict__ b2,
    const float* __restrict__ W3, const float* __restrict__ b3,
    float* __restrict__ s_out) {
  __shared__ float tt[256];
  __shared__ float hh[256];
  const int b = blockIdx.x;
  const int tid = threadIdx.x;
  tt[tid] = t[b * 256 + tid];
  __syncthreads();
  float acc = b1[tid];
  {
    const f4v* wrow = (const f4v*)(W1 + tid * 256);
    #pragma unroll 16
    for (int k = 0; k < 64; ++k) {
      f4v wv = wrow[k];
      acc += wv[0] * tt[4 * k] + wv[1] * tt[4 * k + 1] +
             wv[2] * tt[4 * k + 2] + wv[3] * tt[4 * k + 3];
    }
  }
  float h = acc / (1.0f + expf(-acc));
  __syncthreads();
  hh[tid] = h;
  __syncthreads();
  acc = b2[tid];
  {
    const f4v* wrow = (const f4v*)(W2 + tid * 256);
    #pragma unroll 16
    for (int k = 0; k < 64; ++k) {
      f4v wv = wrow[k];
      acc += wv[0] * hh[4 * k] + wv[1] * hh[4 * k + 1] +
             wv[2] * hh[4 * k + 2] + wv[3] * hh[4 * k + 3];
    }
  }
  h = acc / (1.0f + expf(-acc));
  __syncthreads();
  tt[tid] = h;
  __syncthreads();
  #pragma unroll
  for (int rep = 0; rep < 2; ++rep) {
    const int o = rep * 256 + tid;
    float a3 = b3[o];
    const f4v* wrow = (const f4v*)(W3 + o * 256);
    #pragma unroll 16
    for (int k = 0; k < 64; ++k) {
      f4v wv = wrow[k];
      a3 += wv[0] * tt[4 * k] + wv[1] * tt[4 * k + 1] +
            wv[2] * tt[4 * k + 2] + wv[3] * tt[4 * k + 3];
    }
    s_out[b * 512 + o] = a3 + 1.0f;
  }
}

// ---------------- kernel 2: demod + bw (bf16) [16][512][512] --------------
__global__ __launch_bounds__(256) void modw_kernel(
    const float* __restrict__ weight, const float* __restrict__ s_in,
    unsigned short* __restrict__ bwq) {
  const int tid = threadIdx.x;
  const int wid = (blockIdx.x << 2) | (tid >> 6);
  const int b = wid >> 9;
  const int o = wid & 511;
  const int lane = tid & 63;
  const f4v* wp = (const f4v*)(weight + o * 512 + lane * 8);
  const f4v* sp = (const f4v*)(s_in + b * 512 + lane * 8);
  f4v w0 = wp[0], w1 = wp[1];
  f4v s0 = sp[0], s1 = sp[1];
  float p[8];
  p[0] = w0[0] * s0[0]; p[1] = w0[1] * s0[1];
  p[2] = w0[2] * s0[2]; p[3] = w0[3] * s0[3];
  p[4] = w1[0] * s1[0]; p[5] = w1[1] * s1[1];
  p[6] = w1[2] * s1[2]; p[7] = w1[3] * s1[3];
  float ss = 0.0f;
  #pragma unroll
  for (int i = 0; i < 8; ++i) ss += p[i] * p[i];
  #pragma unroll
  for (int off = 32; off; off >>= 1) ss += __shfl_xor(ss, off);
  const float d = rsqrtf(ss + 1e-8f);
  uint4 outw;
  outw.x = pack2bf(p[0] * d, p[1] * d);
  outw.y = pack2bf(p[2] * d, p[3] * d);
  outw.z = pack2bf(p[4] * d, p[5] * d);
  outw.w = pack2bf(p[6] * d, p[7] * d);
  *(uint4*)(bwq + ((size_t)(b * 512 + o)) * 512 + lane * 8) = outw;
}

// ---------------- kernel 2b: transpose+cast x -> xT [b][l][i] bf16 --------
// tile: [128 i][64 l] per block. grid = 16 b * 4 it * 64 lt = 4096.
__global__ __launch_bounds__(256) void xcastT_kernel(
    const float* __restrict__ x, unsigned short* __restrict__ xT) {
  __shared__ unsigned short lds[64 * 128];  // 16 KB; row l: 128 ushort
  const int bidx = blockIdx.x;
  const int lt = bidx & 63;
  const int it = (bidx >> 6) & 3;
  const int b  = bidx >> 8;
  const int tid = threadIdx.x;

  // phase 1: read x rows (coalesced along l), cast, store transposed-ish
  const int l_lo = tid & 15;   // *4 floats -> covers 64 l
  const int i_pt = tid >> 4;   // 0..15; i = j*16 + i_pt
  const float* src =
      x + ((size_t)(b * 512 + it * 128 + i_pt)) * 4096 + lt * 64 + l_lo * 4;
  #pragma unroll
  for (int j = 0; j < 8; ++j) {
    f4v v = *(const f4v*)(src + (size_t)j * 16 * 4096);
    const int i = j * 16 + i_pt;
    const int g = i >> 3;
    #pragma unroll
    for (int c = 0; c < 4; ++c) {
      const int l = l_lo * 4 + c;
      const int pg = g ^ (l & 15);
      lds[l * 128 + pg * 8 + (i & 7)] =
          __builtin_bit_cast(unsigned short, (__bf16)v[c]);
    }
  }
  __syncthreads();

  // phase 2: write xT rows (l-major), 16B granules, swizzle-matched reads
  const int l_loc = tid >> 2;  // 0..63
  const int iq = tid & 3;
  unsigned short* dst =
      xT + ((size_t)(b * 4096 + lt * 64 + l_loc)) * 512 + it * 128;
  #pragma unroll
  for (int j = 0; j < 4; ++j) {
    const int gi = iq * 4 + j;             // logical 8-i granule
    const int pg = gi ^ (l_loc & 15);
    uint4 val = *(const uint4*)&lds[l_loc * 128 + pg * 8];
    *(uint4*)(dst + gi * 8) = val;
  }
}

// ---------------- kernel 3: batched GEMM out[b] = bw[b] @ xT[b]^T ---------
// m97 structure: both operands staged via global_load_lds (linear dest,
// source pre-swizzled), single-buffered LDS, 2 barriers per K-step.
// Overlap comes from ~4 resident blocks/CU. LDS layout (R4-verified):
// granule (kq, idx) at byte kq*2048 + (idx ^ ((idx>>3)&7))*16.
__global__ __launch_bounds__(256) void gemm_kernel(
    const unsigned short* __restrict__ xT,
    const unsigned short* __restrict__ bwq, float* __restrict__ out) {
  __shared__ __align__(16) unsigned short As[4096];  // 8 KB
  __shared__ __align__(16) unsigned short Bs[4096];  // 8 KB

  const int bid = blockIdx.x;
  const int swz = ((bid & 7) << 8) | (bid >> 3);
  const int mt = swz & 3;            // mt innermost: 4 blocks share xT panel
  const int nt = (swz >> 2) & 31;
  const int bb = swz >> 7;

  const int tid = threadIdx.x;
  const int lane = tid & 63;
  const int wv = tid >> 6;
  const int wr = wv >> 1, wc = wv & 1;

  const unsigned short* abase = bwq + ((size_t)(bb * 512 + mt * 128)) * 512;
  const unsigned short* bbase = xT + ((size_t)(bb * 4096 + nt * 128)) * 512;

  // staging: thread handles slots tid and tid+256 for each of A and B
  const int s0 = tid, s1 = 256 + tid;
  const int kq0 = s0 >> 7, p0 = s0 & 127;
  const int kq1 = s1 >> 7, p1 = s1 & 127;
  const int i0 = p0 ^ ((p0 >> 3) & 7);   // source row (XOR-swizzled)
  const int i1 = p1 ^ ((p1 >> 3) & 7);
  const unsigned short* asrc0 = abase + i0 * 512 + kq0 * 8;
  const unsigned short* asrc1 = abase + i1 * 512 + kq1 * 8;
  const unsigned short* bsrc0 = bbase + i0 * 512 + kq0 * 8;
  const unsigned short* bsrc1 = bbase + i1 * 512 + kq1 * 8;
  unsigned short* adst0 = As + s0 * 8;
  unsigned short* adst1 = As + s1 * 8;
  unsigned short* bdst0 = Bs + s0 * 8;
  unsigned short* bdst1 = Bs + s1 * 8;

  // fragment read offsets (R4-verified)
  const int kqL = lane >> 4;
  const int rL = lane & 15;
  int aro[4], bro[4];
  #pragma unroll
  for (int i = 0; i < 4; ++i) {
    const int m = wr * 64 + i * 16 + rL;
    aro[i] = kqL * 2048 + (m ^ ((m >> 3) & 7)) * 16;
    const int n = wc * 64 + i * 16 + rL;
    bro[i] = kqL * 2048 + (n ^ ((n >> 3) & 7)) * 16;
  }

  f32x4 acc[4][4] = {};

  #pragma unroll
  for (int it = 0; it < 16; ++it) {
    const int ko = it * 32;  // ushort offset along k
    GLDS16(asrc0 + ko, adst0);
    GLDS16(asrc1 + ko, adst1);
    GLDS16(bsrc0 + ko, bdst0);
    GLDS16(bsrc1 + ko, bdst1);
    __syncthreads();  // drains this wave's DMA (vmcnt0) + syncs block

    {
      const char* ab = (const char*)As;
      const char* bbuf = (const char*)Bs;
      bf16x8 a0 = *(const bf16x8*)(ab + aro[0]);
      bf16x8 a1 = *(const bf16x8*)(ab + aro[1]);
      bf16x8 a2 = *(const bf16x8*)(ab + aro[2]);
      bf16x8 a3 = *(const bf16x8*)(ab + aro[3]);
      bf16x8 bf0 = *(const bf16x8*)(bbuf + bro[0]);
      bf16x8 bf1 = *(const bf16x8*)(bbuf + bro[1]);
      bf16x8 bf2 = *(const bf16x8*)(bbuf + bro[2]);
      bf16x8 bf3 = *(const bf16x8*)(bbuf + bro[3]);
      acc[0][0] = __builtin_amdgcn_mfma_f32_16x16x32_bf16(a0, bf0, acc[0][0], 0, 0, 0);
      acc[0][1] = __builtin_amdgcn_mfma_f32_16x16x32_bf16(a0, bf1, acc[0][1], 0, 0, 0);
      acc[0][2] = __builtin_amdgcn_mfma_f32_16x16x32_bf16(a0, bf2, acc[0][2], 0, 0, 0);
      acc[0][3] = __builtin_amdgcn_mfma_f32_16x16x32_bf16(a0, bf3, acc[0][3], 0, 0, 0);
      acc[1][0] = __builtin_amdgcn_mfma_f32_16x16x32_bf16(a1, bf0, acc[1][0], 0, 0, 0);
      acc[1][1] = __builtin_amdgcn_mfma_f32_16x16x32_bf16(a1, bf1, acc[1][1], 0, 0, 0);
      acc[1][2] = __builtin_amdgcn_mfma_f32_16x16x32_bf16(a1, bf2, acc[1][2], 0, 0, 0);
      acc[1][3] = __builtin_amdgcn_mfma_f32_16x16x32_bf16(a1, bf3, acc[1][3], 0, 0, 0);
      acc[2][0] = __builtin_amdgcn_mfma_f32_16x16x32_bf16(a2, bf0, acc[2][0], 0, 0, 0);
      acc[2][1] = __builtin_amdgcn_mfma_f32_16x16x32_bf16(a2, bf1, acc[2][1], 0, 0, 0);
      acc[2][2] = __builtin_amdgcn_mfma_f32_16x16x32_bf16(a2, bf2, acc[2][2], 0, 0, 0);
      acc[2][3] = __builtin_amdgcn_mfma_f32_16x16x32_bf16(a2, bf3, acc[2][3], 0, 0, 0);
      acc[3][0] = __builtin_amdgcn_mfma_f32_16x16x32_bf16(a3, bf0, acc[3][0], 0, 0, 0);
      acc[3][1] = __builtin_amdgcn_mfma_f32_16x16x32_bf16(a3, bf1, acc[3][1], 0, 0, 0);
      acc[3][2] = __builtin_amdgcn_mfma_f32_16x16x32_bf16(a3, bf2, acc[3][2], 0, 0, 0);
      acc[3][3] = __builtin_amdgcn_mfma_f32_16x16x32_bf16(a3, bf3, acc[3][3], 0, 0, 0);
    }
    __syncthreads();  // protect As/Bs rewrite next step
  }

  // epilogue (R1..R4-verified mapping)
  const size_t ob =
      ((size_t)(bb * 512 + mt * 128 + wr * 64 + ((lane >> 4) << 2))) * 4096 +
      nt * 128 + wc * 64 + (lane & 15);
  #pragma unroll
  for (int mi = 0; mi < 4; ++mi)
    #pragma unroll
    for (int ni = 0; ni < 4; ++ni)
      #pragma unroll
      for (int jj = 0; jj < 4; ++jj)
        out[ob + (size_t)(mi * 16 + jj) * 4096 + ni * 16] = acc[mi][ni][jj];
}

extern "C" void kernel_launch(void* const* d_in, const int* in_sizes, int n_in,
                              void* d_out, int out_size, void* d_ws, size_t ws_size,
                              hipStream_t stream) {
  const float* x      = (const float*)d_in[0];
  const float* t      = (const float*)d_in[1];
  const float* weight = (const float*)d_in[2];
  const float* W1     = (const float*)d_in[3];
  const float* b1     = (const float*)d_in[4];
  const float* W2     = (const float*)d_in[5];
  const float* b2     = (const float*)d_in[6];
  const float* W3     = (const float*)d_in[7];
  const float* b3     = (const float*)d_in[8];
  float* out = (float*)d_out;

  // ws layout: s (32 KB) | bwq (8 MB) | xT (64 MB)
  float* s_ws = (float*)d_ws;
  unsigned short* bwq = (unsigned short*)((char*)d_ws + 32 * 1024);
  unsigned short* xTb = (unsigned short*)((char*)d_ws + 32 * 1024 + 8 * 1024 * 1024);

  mlp_kernel<<<16, 256, 0, stream>>>(t, W1, b1, W2, b2, W3, b3, s_ws);
  xcastT_kernel<<<4096, 256, 0, stream>>>(x, xTb);
  modw_kernel<<<2048, 256, 0, stream>>>(weight, s_ws, bwq);
  gemm_kernel<<<2048, 256, 0, stream>>>(xTb, bwq, out);
}

// Round 6
// 144.343 us; speedup vs baseline: 1.1180x; 1.1180x over previous
//
#include <hip/hip_runtime.h>
#include <hip/hip_bf16.h>

typedef float f4v __attribute__((ext_vector_type(4)));
typedef float f32x4 __attribute__((ext_vector_type(4)));
typedef __bf16 bf16x8 __attribute__((ext_vector_type(8)));

#define GLDS16(gsrc, ldst)                                                  \
  __builtin_amdgcn_global_load_lds(                                         \
      (const __attribute__((address_space(1))) unsigned int*)(gsrc),        \
      (__attribute__((address_space(3))) unsigned int*)(ldst), 16, 0, 0)

__device__ __forceinline__ unsigned pack2bf(float lo, float hi) {
  unsigned short ua = __builtin_bit_cast(unsigned short, (__bf16)lo);
  unsigned short ub = __builtin_bit_cast(unsigned short, (__bf16)hi);
  return (unsigned)ua | ((unsigned)ub << 16);
}

// ---------------- kernel 1: modulation MLP -> s [16][512] (f32, ws) -------
__global__ __launch_bounds__(256) void mlp_kernel(
    const float* __restrict__ t,
    const float* __restrict__ W1, const float* __restrict__ b1,
    const float* __restrict__ W2, const float* __restrict__ b2,
    const float* __restrict__ W3, const float* __restrict__ b3,
    float* __restrict__ s_out) {
  __shared__ float tt[256];
  __shared__ float hh[256];
  const int b = blockIdx.x;
  const int tid = threadIdx.x;
  tt[tid] = t[b * 256 + tid];
  __syncthreads();
  float acc = b1[tid];
  {
    const f4v* wrow = (const f4v*)(W1 + tid * 256);
    #pragma unroll 16
    for (int k = 0; k < 64; ++k) {
      f4v wv = wrow[k];
      acc += wv[0] * tt[4 * k] + wv[1] * tt[4 * k + 1] +
             wv[2] * tt[4 * k + 2] + wv[3] * tt[4 * k + 3];
    }
  }
  float h = acc / (1.0f + expf(-acc));
  __syncthreads();
  hh[tid] = h;
  __syncthreads();
  acc = b2[tid];
  {
    const f4v* wrow = (const f4v*)(W2 + tid * 256);
    #pragma unroll 16
    for (int k = 0; k < 64; ++k) {
      f4v wv = wrow[k];
      acc += wv[0] * hh[4 * k] + wv[1] * hh[4 * k + 1] +
             wv[2] * hh[4 * k + 2] + wv[3] * hh[4 * k + 3];
    }
  }
  h = acc / (1.0f + expf(-acc));
  __syncthreads();
  tt[tid] = h;
  __syncthreads();
  #pragma unroll
  for (int rep = 0; rep < 2; ++rep) {
    const int o = rep * 256 + tid;
    float a3 = b3[o];
    const f4v* wrow = (const f4v*)(W3 + o * 256);
    #pragma unroll 16
    for (int k = 0; k < 64; ++k) {
      f4v wv = wrow[k];
      a3 += wv[0] * tt[4 * k] + wv[1] * tt[4 * k + 1] +
            wv[2] * tt[4 * k + 2] + wv[3] * tt[4 * k + 3];
    }
    s_out[b * 512 + o] = a3 + 1.0f;
  }
}

// ---------------- kernel 2: demod + bw (bf16) [16][512][512] --------------
__global__ __launch_bounds__(256) void modw_kernel(
    const float* __restrict__ weight, const float* __restrict__ s_in,
    unsigned short* __restrict__ bwq) {
  const int tid = threadIdx.x;
  const int wid = (blockIdx.x << 2) | (tid >> 6);
  const int b = wid >> 9;
  const int o = wid & 511;
  const int lane = tid & 63;
  const f4v* wp = (const f4v*)(weight + o * 512 + lane * 8);
  const f4v* sp = (const f4v*)(s_in + b * 512 + lane * 8);
  f4v w0 = wp[0], w1 = wp[1];
  f4v s0 = sp[0], s1 = sp[1];
  float p[8];
  p[0] = w0[0] * s0[0]; p[1] = w0[1] * s0[1];
  p[2] = w0[2] * s0[2]; p[3] = w0[3] * s0[3];
  p[4] = w1[0] * s1[0]; p[5] = w1[1] * s1[1];
  p[6] = w1[2] * s1[2]; p[7] = w1[3] * s1[3];
  float ss = 0.0f;
  #pragma unroll
  for (int i = 0; i < 8; ++i) ss += p[i] * p[i];
  #pragma unroll
  for (int off = 32; off; off >>= 1) ss += __shfl_xor(ss, off);
  const float d = rsqrtf(ss + 1e-8f);
  uint4 outw;
  outw.x = pack2bf(p[0] * d, p[1] * d);
  outw.y = pack2bf(p[2] * d, p[3] * d);
  outw.z = pack2bf(p[4] * d, p[5] * d);
  outw.w = pack2bf(p[6] * d, p[7] * d);
  *(uint4*)(bwq + ((size_t)(b * 512 + o)) * 512 + lane * 8) = outw;
}

// ---------------- kernel 3: fused GEMM out[b] = bw[b] @ x[b] --------------
// A = bw bf16 [128m][32k] LDS (XOR-source-swizzled GLDS, R5-verified).
// B = x f32 [32k][128n] LDS (GLDS direct, granule XOR swizzle via source;
//     fragment = 8 strided ds_read_b32 + cast -> 2-way banks = free).
// Double-buffered, one __syncthreads per K-step, STAGE(it+1) issued BEFORE
// COMPUTE(it) so the sync's vmcnt(0) drain lands after a compute phase.
__global__ __launch_bounds__(256) void gemm_kernel(
    const float* __restrict__ x, const unsigned short* __restrict__ bwq,
    float* __restrict__ out) {
  __shared__ __align__(16) unsigned short As[2][4096];  // 16 KB
  __shared__ __align__(16) float Bs[2][4096];           // 32 KB

  const int bid = blockIdx.x;
  const int swz = ((bid & 7) << 8) | (bid >> 3);
  const int mt = swz & 3;            // mt innermost: 4 blocks share x panel
  const int nt = (swz >> 2) & 31;
  const int bb = swz >> 7;

  const int tid = threadIdx.x;
  const int lane = tid & 63;
  const int wv = tid >> 6;
  const int wr = wv >> 1, wc = wv & 1;

  const unsigned short* abase = bwq + ((size_t)(bb * 512 + mt * 128)) * 512;
  const float* xbase = x + ((size_t)bb * 512) * 4096 + nt * 128;

  // ---- A staging (R5-verified): slots tid, tid+256 ----------------------
  const int s0 = tid, s1 = 256 + tid;
  const int kq0 = s0 >> 7, p0 = s0 & 127;
  const int kq1 = s1 >> 7, p1 = s1 & 127;
  const int i0 = p0 ^ ((p0 >> 3) & 7);
  const int i1 = p1 ^ ((p1 >> 3) & 7);
  const unsigned short* asrc0 = abase + i0 * 512 + kq0 * 8;
  const unsigned short* asrc1 = abase + i1 * 512 + kq1 * 8;

  // ---- B staging: 4 slots (tid + 256r); source granule pre-swizzled -----
  // LDS phys granule p holds logical granule (p&31)^(((k>>3)&1)<<2) of row k
  const float* bsrc[4];
  #pragma unroll
  for (int r = 0; r < 4; ++r) {
    const int sl = tid + 256 * r;
    const int k = sl >> 5;           // 0..31
    const int gp = sl & 31;          // phys granule in row
    const int gl = gp ^ (((k >> 3) & 1) << 2);
    bsrc[r] = xbase + (size_t)k * 4096 + gl * 4;
  }

  // ---- fragment read offsets --------------------------------------------
  const int kqL = lane >> 4;
  const int rL = lane & 15;
  int aro[4];
  #pragma unroll
  for (int i = 0; i < 4; ++i) {
    const int m = wr * 64 + i * 16 + rL;
    aro[i] = kqL * 2048 + (m ^ ((m >> 3) & 7)) * 16;  // bytes
  }
  int bro[4];
  #pragma unroll
  for (int i = 0; i < 4; ++i) {
    const int nb = wc * 64 + i * 16 + rL;
    const int g = (nb >> 2) ^ ((kqL & 1) << 2);
    bro[i] = kqL * 1024 + g * 4 + (nb & 3);           // float units
  }

  f32x4 acc[4][4] = {};

#define STAGE(IT, BUF)                                                      \
  do {                                                                      \
    const int _ko = (IT) * 32;                                              \
    GLDS16(asrc0 + _ko, &As[BUF][s0 * 8]);                                  \
    GLDS16(asrc1 + _ko, &As[BUF][s1 * 8]);                                  \
    GLDS16(bsrc[0] + (size_t)_ko * 4096, &Bs[BUF][(tid + 0) * 4]);          \
    GLDS16(bsrc[1] + (size_t)_ko * 4096, &Bs[BUF][(tid + 256) * 4]);        \
    GLDS16(bsrc[2] + (size_t)_ko * 4096, &Bs[BUF][(tid + 512) * 4]);        \
    GLDS16(bsrc[3] + (size_t)_ko * 4096, &Bs[BUF][(tid + 768) * 4]);        \
  } while (0)

  // prologue
  STAGE(0, 0);
  __syncthreads();

  #pragma unroll
  for (int it = 0; it < 16; ++it) {
    const int cur = it & 1;
    if (it < 15) STAGE(it + 1, cur ^ 1);

    {
      const char* ab = (const char*)&As[cur][0];
      const float* bbuf = &Bs[cur][0];
      bf16x8 a0 = *(const bf16x8*)(ab + aro[0]);
      bf16x8 a1 = *(const bf16x8*)(ab + aro[1]);
      bf16x8 a2 = *(const bf16x8*)(ab + aro[2]);
      bf16x8 a3 = *(const bf16x8*)(ab + aro[3]);
      #pragma unroll
      for (int ni = 0; ni < 4; ++ni) {
        const float* bp = bbuf + bro[ni];
        bf16x8 bf;
        bf[0] = (__bf16)bp[0 * 128];
        bf[1] = (__bf16)bp[1 * 128];
        bf[2] = (__bf16)bp[2 * 128];
        bf[3] = (__bf16)bp[3 * 128];
        bf[4] = (__bf16)bp[4 * 128];
        bf[5] = (__bf16)bp[5 * 128];
        bf[6] = (__bf16)bp[6 * 128];
        bf[7] = (__bf16)bp[7 * 128];
        acc[0][ni] = __builtin_amdgcn_mfma_f32_16x16x32_bf16(a0, bf, acc[0][ni], 0, 0, 0);
        acc[1][ni] = __builtin_amdgcn_mfma_f32_16x16x32_bf16(a1, bf, acc[1][ni], 0, 0, 0);
        acc[2][ni] = __builtin_amdgcn_mfma_f32_16x16x32_bf16(a2, bf, acc[2][ni], 0, 0, 0);
        acc[3][ni] = __builtin_amdgcn_mfma_f32_16x16x32_bf16(a3, bf, acc[3][ni], 0, 0, 0);
      }
    }
    __syncthreads();  // drains STAGE(it+1) after a full compute of cover
  }

  // epilogue (verified mapping)
  const size_t ob =
      ((size_t)(bb * 512 + mt * 128 + wr * 64 + ((lane >> 4) << 2))) * 4096 +
      nt * 128 + wc * 64 + (lane & 15);
  #pragma unroll
  for (int mi = 0; mi < 4; ++mi)
    #pragma unroll
    for (int ni = 0; ni < 4; ++ni)
      #pragma unroll
      for (int jj = 0; jj < 4; ++jj)
        out[ob + (size_t)(mi * 16 + jj) * 4096 + ni * 16] = acc[mi][ni][jj];

#undef STAGE
}

extern "C" void kernel_launch(void* const* d_in, const int* in_sizes, int n_in,
                              void* d_out, int out_size, void* d_ws, size_t ws_size,
                              hipStream_t stream) {
  const float* x      = (const float*)d_in[0];
  const float* t      = (const float*)d_in[1];
  const float* weight = (const float*)d_in[2];
  const float* W1     = (const float*)d_in[3];
  const float* b1     = (const float*)d_in[4];
  const float* W2     = (const float*)d_in[5];
  const float* b2     = (const float*)d_in[6];
  const float* W3     = (const float*)d_in[7];
  const float* b3     = (const float*)d_in[8];
  float* out = (float*)d_out;

  float* s_ws = (float*)d_ws;                                   // 32 KB
  unsigned short* bwq = (unsigned short*)((char*)d_ws + 32 * 1024);  // 8 MB

  mlp_kernel<<<16, 256, 0, stream>>>(t, W1, b1, W2, b2, W3, b3, s_ws);
  modw_kernel<<<2048, 256, 0, stream>>>(weight, s_ws, bwq);
  gemm_kernel<<<2048, 256, 0, stream>>>(x, bwq, out);
}